// Round 3
// baseline (451.731 us; speedup 1.0000x reference)
//
#include <hip/hip_runtime.h>
#include <math.h>

#define N_NODES 50000
#define N_EDGES 600000
#define BATCH 16
#define SEQ 512
#define NROWS (BATCH*SEQ)   // 8192
#define N_ITEMS (N_EDGES + N_NODES)

// ---- workspace layout (float offsets) ----
#define OFF_XW     0L
#define OFF_X      (OFF_XW + 6400000L)
#define OFF_ACC    (OFF_X + 1048576L)
#define OFF_AS     (OFF_ACC + 1048576L)
#define OFF_AD     (OFF_AS + 50000L)
#define OFF_WC     (OFF_AD + 50000L)
#define OFF_BC     (OFF_WC + 16384L)
#define OFF_QP     (OFF_BC + 128L)
#define OFF_WKH    (OFF_QP + 384L)
#define OFF_CKH    (OFF_WKH + 1536L)
#define OFF_VPOD   (OFF_CKH + 16L)
// ---- zeroed-every-launch block (one memset) ----
#define OFF_MASK   (OFF_VPOD + 2048L)
#define OFF_DEG    (OFF_MASK + 50000L)
#define OFF_FILL   (OFF_DEG + 8192L)
#define OFF_CNT    (OFF_FILL + 8192L)          // [cnt, npairs, pad, pad]
#define ZERO_BYTES ((50000L + 8192L + 8192L + 4L) * 4L)
// ---- end zeroed block ----
#define OFF_MAP    (OFF_CNT + 4L)
#define OFF_INV    (OFF_MAP + 50000L)
#define OFF_ROWPTR (OFF_INV + 8192L)
#define OFF_PAIRS  (OFF_ROWPTR + 8194L)        // int2 x 650000
#define OFF_COL    (OFF_PAIRS + 1300000L)

// ---------------- prep: Wc = lin_W @ gat_W, bc = lin_b @ gat_W, qp for mabs 0/2/4 ----------------
__global__ __launch_bounds__(256) void prep_kernel(
    const float* __restrict__ lin_W, const float* __restrict__ lin_b,
    const float* __restrict__ gat_W,
    const float* __restrict__ mab_Wq, const float* __restrict__ mab_bq,
    const float* __restrict__ isab_I, const float* __restrict__ pma_S,
    float* __restrict__ Wc, float* __restrict__ bc, float* __restrict__ qp)
{
    int t = blockIdx.x * 256 + threadIdx.x;
    if (t < 16384) {
        int i = t >> 7, j = t & 127;
        float s = 0.f;
        for (int k = 0; k < 128; ++k) s += lin_W[i*128 + k] * gat_W[k*128 + j];
        Wc[t] = s;
    } else if (t < 16512) {
        int j = t - 16384;
        float s = 0.f;
        for (int k = 0; k < 128; ++k) s += lin_b[k] * gat_W[k*128 + j];
        bc[j] = s;
    } else if (t < 16896) {
        int u = t - 16512;
        int m = u >> 7, c = u & 127;
        int mi = m * 2;   // mab index 0, 2, 4
        const float* vec = (m == 0) ? isab_I : (m == 1 ? isab_I + 128 : pma_S);
        float s = mab_bq[mi*128 + c];
        for (int k = 0; k < 128; ++k) s += vec[k] * mab_Wq[mi*16384 + k*128 + c];
        qp[u] = s;
    }
}

// ---------------- prep2: head logit vectors wk_h = Wk[:,h-slice] @ qp_h, ck_h = bk_h . qp_h ------
__global__ __launch_bounds__(256) void prep2_kernel(
    const float* __restrict__ mab_Wk, const float* __restrict__ mab_bk,
    const float* __restrict__ qp, float* __restrict__ wkh, float* __restrict__ ckh)
{
    int t = blockIdx.x * 256 + threadIdx.x;
    if (t < 1536) {
        int m = t >> 9;           // 0..2 -> mab 0,2,4
        int h = (t >> 7) & 3;
        int j = t & 127;
        int mi = m * 2;
        const float* Wk = mab_Wk + mi*16384 + j*128 + h*32;
        const float* q  = qp + m*128 + h*32;
        float s = 0.f;
        #pragma unroll
        for (int d = 0; d < 32; ++d) s += Wk[d] * q[d];
        wkh[t] = s;
    } else if (t < 1548) {
        int u = t - 1536;         // m*4 + h
        int m = u >> 2, h = u & 3;
        int mi = m * 2;
        const float* bk = mab_bk + mi*128 + h*32;
        const float* q  = qp + m*128 + h*32;
        float s = 0.f;
        #pragma unroll
        for (int d = 0; d < 32; ++d) s += bk[d] * q[d];
        ckh[u] = s;
    }
}

// ---------------- gemm0: xw = node_embed[:N] @ Wc + bc -----------------------------------------
__global__ __launch_bounds__(256) void gemm0_kernel(
    const float* __restrict__ Xin, const float* __restrict__ W1,
    const float* __restrict__ b1, float* __restrict__ out1)
{
    __shared__ float Xs[16][128];
    int t = threadIdx.x;
    long row0 = (long)blockIdx.x * 16;
    #pragma unroll
    for (int i = 0; i < 8; ++i) {
        int idx = i*256 + t;
        int r = idx >> 7, k = idx & 127;
        Xs[r][k] = Xin[(row0 + r)*128 + k];
    }
    __syncthreads();
    int c  = t & 127;
    int hh = t >> 7;
    float acc1[8];
    #pragma unroll
    for (int r = 0; r < 8; ++r) acc1[r] = 0.f;
    for (int k4 = 0; k4 < 128; k4 += 4) {
        float xv[8][4];
        #pragma unroll
        for (int r = 0; r < 8; ++r) {
            float4 tmp = *(const float4*)&Xs[hh*8 + r][k4];
            xv[r][0] = tmp.x; xv[r][1] = tmp.y; xv[r][2] = tmp.z; xv[r][3] = tmp.w;
        }
        #pragma unroll
        for (int kk = 0; kk < 4; ++kk) {
            float w1 = W1[(k4 + kk)*128 + c];
            #pragma unroll
            for (int r = 0; r < 8; ++r) acc1[r] += xv[r][kk] * w1;
        }
    }
    float bb = b1[c];
    #pragma unroll
    for (int r = 0; r < 8; ++r) out1[(row0 + hh*8 + r)*128 + c] = acc1[r] + bb;
}

// ---------------- fused odd-MAB: Xout = O1 + relu(O1@Wo+bo), O1 = X@Wq+bq+vpod[b] ---------------
__global__ __launch_bounds__(256) void gemm_odd_kernel(
    const float* __restrict__ X, const float* __restrict__ Wq,
    const float* __restrict__ bq, const float* __restrict__ vpod,
    const float* __restrict__ Wo, const float* __restrict__ bo,
    float* __restrict__ Xout)
{
    __shared__ float Xs[16][128];
    __shared__ float O1[16][128];
    int t = threadIdx.x;
    long row0 = (long)blockIdx.x * 16;
    int bidx = (int)(row0 >> 9);
    #pragma unroll
    for (int i = 0; i < 8; ++i) {
        int idx = i*256 + t;
        int r = idx >> 7, k = idx & 127;
        Xs[r][k] = X[(row0 + r)*128 + k];
    }
    __syncthreads();
    int c  = t & 127;
    int hh = t >> 7;
    float acc[8];
    #pragma unroll
    for (int r = 0; r < 8; ++r) acc[r] = 0.f;
    for (int k4 = 0; k4 < 128; k4 += 4) {
        float xv[8][4];
        #pragma unroll
        for (int r = 0; r < 8; ++r) {
            float4 tmp = *(const float4*)&Xs[hh*8 + r][k4];
            xv[r][0] = tmp.x; xv[r][1] = tmp.y; xv[r][2] = tmp.z; xv[r][3] = tmp.w;
        }
        #pragma unroll
        for (int kk = 0; kk < 4; ++kk) {
            float w = Wq[(k4 + kk)*128 + c];
            #pragma unroll
            for (int r = 0; r < 8; ++r) acc[r] += xv[r][kk] * w;
        }
    }
    float bb = bq[c] + vpod[bidx*128 + c];
    #pragma unroll
    for (int r = 0; r < 8; ++r) O1[hh*8 + r][c] = acc[r] + bb;
    __syncthreads();
    #pragma unroll
    for (int r = 0; r < 8; ++r) acc[r] = 0.f;
    for (int k4 = 0; k4 < 128; k4 += 4) {
        float xv[8][4];
        #pragma unroll
        for (int r = 0; r < 8; ++r) {
            float4 tmp = *(const float4*)&O1[hh*8 + r][k4];
            xv[r][0] = tmp.x; xv[r][1] = tmp.y; xv[r][2] = tmp.z; xv[r][3] = tmp.w;
        }
        #pragma unroll
        for (int kk = 0; kk < 4; ++kk) {
            float w = Wo[(k4 + kk)*128 + c];
            #pragma unroll
            for (int r = 0; r < 8; ++r) acc[r] += xv[r][kk] * w;
        }
    }
    float bb2 = bo[c];
    #pragma unroll
    for (int r = 0; r < 8; ++r)
        Xout[(row0 + hh*8 + r)*128 + c] = O1[hh*8 + r][c] + fmaxf(acc[r] + bb2, 0.f);
}

// ---------------- per-node attention scalars a_s, a_d ----------------
__global__ __launch_bounds__(256) void avec_kernel(
    const float* __restrict__ xw, const float* __restrict__ att_src,
    const float* __restrict__ att_dst, float* __restrict__ a_s, float* __restrict__ a_d)
{
    int w = threadIdx.x >> 6, lane = threadIdx.x & 63;
    long row = (long)blockIdx.x * 4 + w;
    const float* xr = xw + row*128 + lane*2;
    float x0 = xr[0], x1 = xr[1];
    float s = x0*att_src[lane*2] + x1*att_src[lane*2 + 1];
    float d = x0*att_dst[lane*2] + x1*att_dst[lane*2 + 1];
    #pragma unroll
    for (int off = 32; off > 0; off >>= 1) {
        s += __shfl_down(s, off);
        d += __shfl_down(d, off);
    }
    if (lane == 0) { a_s[row] = s; a_d[row] = d; }
}

// ---------------- mark needed destination nodes ----------------
__global__ void maskset_kernel(const int* __restrict__ node_ids, int* __restrict__ mask)
{
    int i = blockIdx.x*256 + threadIdx.x;
    if (i < NROWS) mask[node_ids[i]] = 1;
}

// ---------------- assign compact indices + inverse map ----------------
__global__ void assign_kernel(const int* __restrict__ mask, int* __restrict__ map,
                              int* __restrict__ inv, int* __restrict__ counter)
{
    int i = blockIdx.x*256 + threadIdx.x;
    if (i >= N_NODES) return;
    int c = -1;
    if (mask[i]) { c = atomicAdd(counter, 1); inv[c] = i; }
    map[i] = c;
}

// ---------------- pass1: per-dest degree count + compact masked (src, c) pairs ------------------
__global__ __launch_bounds__(256) void pass1_kernel(
    const int* __restrict__ edge_idx, const int* __restrict__ map,
    int* __restrict__ deg, int* __restrict__ npairs, int2* __restrict__ pairs)
{
    int i = blockIdx.x*256 + threadIdx.x;
    bool act = false;
    int s = 0, c = 0;
    if (i < N_ITEMS) {
        int dd;
        if (i < N_EDGES) { s = edge_idx[i]; dd = edge_idx[N_EDGES + i]; }
        else             { s = dd = i - N_EDGES; }
        c = map[dd];
        act = (c >= 0);
    }
    if (act) atomicAdd(&deg[c], 1);
    unsigned long long m = __ballot(act);
    if (m == 0ull) return;
    int lane = threadIdx.x & 63;
    int leader = __ffsll((long long)m) - 1;
    int base = 0;
    if (lane == leader) base = atomicAdd(npairs, __popcll(m));
    base = __shfl(base, leader);
    if (act) {
        int pos = base + __popcll(m & ((1ull << lane) - 1ull));
        pairs[pos] = make_int2(s, c);
    }
}

// ---------------- exclusive scan of deg[0..8191] -> rowptr[0..8192] (single block) --------------
__global__ __launch_bounds__(256) void scan_kernel(const int* __restrict__ deg,
                                                   int* __restrict__ rowptr)
{
    __shared__ int part[256];
    __shared__ int pref[256];
    int t = threadIdx.x;
    int base = t * 32;
    int s = 0;
    #pragma unroll
    for (int j = 0; j < 32; ++j) s += deg[base + j];
    part[t] = s;
    __syncthreads();
    if (t == 0) {
        int run = 0;
        for (int i = 0; i < 256; ++i) { pref[i] = run; run += part[i]; }
    }
    __syncthreads();
    int run = pref[t];
    #pragma unroll
    for (int j = 0; j < 32; ++j) { rowptr[base + j] = run; run += deg[base + j]; }
    if (t == 255) rowptr[8192] = run;
}

// ---------------- pass2: fill CSR column lists ----------------
__global__ void pass2_kernel(const int2* __restrict__ pairs, const int* __restrict__ npairs,
                             const int* __restrict__ rowptr, int* __restrict__ fill,
                             int* __restrict__ colx)
{
    int i = blockIdx.x*256 + threadIdx.x;
    if (i >= *npairs) return;
    int2 p = pairs[i];
    int pos = rowptr[p.y] + atomicAdd(&fill[p.y], 1);
    colx[pos] = p.x;
}

// ---------------- aggregate: one wave per masked destination, zero f32 atomics ------------------
__global__ __launch_bounds__(256) void agg_kernel(
    const int* __restrict__ rowptr, const int* __restrict__ colx,
    const int* __restrict__ inv, const int* __restrict__ cnt,
    const float* __restrict__ a_s, const float* __restrict__ a_d,
    const float* __restrict__ xw, float* __restrict__ acc)
{
    int c = blockIdx.x*4 + (threadIdx.x >> 6);
    int lane = threadIdx.x & 63;
    if (c >= *cnt) return;
    int dd = inv[c];
    float ad = a_d[dd];
    int beg = rowptr[c], end = rowptr[c + 1];
    float s0 = 0.f, s1 = 0.f, den = 0.f;
    for (int j = beg; j < end; ++j) {
        int s = colx[j];
        float e = a_s[s] + ad;
        e = (e > 0.f) ? e : 0.2f * e;
        float ex = __expf(e);
        den += ex;
        float2 v = *(const float2*)(xw + (long)s*128 + lane*2);
        s0 += ex * v.x;
        s1 += ex * v.y;
    }
    float inv_d = 1.f / den;
    float* o = acc + (long)c*128 + lane*2;
    o[0] = s0 * inv_d;
    o[1] = s1 * inv_d;
}

// ---------------- gather sampled node rows: + bias ----------------
__global__ __launch_bounds__(256) void gather_kernel(
    const int* __restrict__ node_ids, const int* __restrict__ map,
    const float* __restrict__ acc, const float* __restrict__ gat_bias,
    float* __restrict__ X)
{
    int w = threadIdx.x >> 6, lane = threadIdx.x & 63;
    int j = blockIdx.x*4 + w;
    int c = map[node_ids[j]];
    const float2 v = *(const float2*)(acc + (long)c*128 + lane*2);
    float* o = X + (long)j*128 + lane*2;
    o[0] = v.x + gat_bias[lane*2];
    o[1] = v.y + gat_bias[lane*2 + 1];
}

// ---------------- 128x128 matvec with 512 threads (4-way split-K + LDS reduce) -----------------
__device__ __forceinline__ float matvec_qs(
    const float* __restrict__ W, const float* xs, float (*red)[128], int t)
{
    int c = t & 127, q = t >> 7;
    float acc = 0.f;
    #pragma unroll
    for (int j = 0; j < 32; ++j) {
        int k = q*32 + j;
        acc += xs[k] * W[k*128 + c];
    }
    red[q][c] = acc;
    __syncthreads();
    float s = 0.f;
    if (t < 128) s = red[0][t] + red[1][t] + red[2][t] + red[3][t];
    __syncthreads();
    return s;
}

// ---------------- even MAB via logit-trick: no Kp/Vp materialization ----------------------------
__global__ __launch_bounds__(512) void attn_even_kernel(
    const float* __restrict__ X, const float* __restrict__ qp,
    const float* __restrict__ wkh, const float* __restrict__ ckh,
    const float* __restrict__ Wv, const float* __restrict__ bv,
    const float* __restrict__ Wo, const float* __restrict__ bo,
    const float* __restrict__ Wv1, const float* __restrict__ bv1,
    float* __restrict__ vpod)
{
    __shared__ float l_sm[4][512];
    __shared__ float part[4][4][128];
    __shared__ float wks[4][128];
    __shared__ float u_sm[4][128];
    __shared__ float red[4][128];
    __shared__ float red64[4][64];
    __shared__ float mx[4], dn[4];
    __shared__ float qs[128], Ovec[128], Hsm[128];
    int b = blockIdx.x, t = threadIdx.x;
    if (t < 128) qs[t] = qp[t];
    wks[t >> 7][t & 127] = wkh[t];
    __syncthreads();
    const float scale = 0.088388347648318447f;  // 1/sqrt(128)
    float ck0 = ckh[0], ck1 = ckh[1], ck2 = ckh[2], ck3 = ckh[3];
    {   // logits: l_h[k] = X_k . wk_h + ck_h
        const float* xr = X + ((long)b*512 + t)*128;
        float l[4] = {0.f, 0.f, 0.f, 0.f};
        for (int d4 = 0; d4 < 128; d4 += 4) {
            float4 xv = *(const float4*)&xr[d4];
            #pragma unroll
            for (int h = 0; h < 4; ++h)
                l[h] += xv.x*wks[h][d4] + xv.y*wks[h][d4+1]
                      + xv.z*wks[h][d4+2] + xv.w*wks[h][d4+3];
        }
        l_sm[0][t] = (l[0] + ck0) * scale;
        l_sm[1][t] = (l[1] + ck1) * scale;
        l_sm[2][t] = (l[2] + ck2) * scale;
        l_sm[3][t] = (l[3] + ck3) * scale;
    }
    __syncthreads();
    if (t < 256) {
        int h = t >> 6, i = t & 63;
        float m = -1e30f;
        #pragma unroll
        for (int j = 0; j < 8; ++j) m = fmaxf(m, l_sm[h][i + 64*j]);
        red64[h][i] = m;
    }
    __syncthreads();
    if (t < 4) {
        float m = -1e30f;
        for (int i = 0; i < 64; ++i) m = fmaxf(m, red64[t][i]);
        mx[t] = m;
    }
    __syncthreads();
    #pragma unroll
    for (int h = 0; h < 4; ++h) l_sm[h][t] = __expf(l_sm[h][t] - mx[h]);
    __syncthreads();
    if (t < 256) {
        int h = t >> 6, i = t & 63;
        float ssum = 0.f;
        #pragma unroll
        for (int j = 0; j < 8; ++j) ssum += l_sm[h][i + 64*j];
        red64[h][i] = ssum;
    }
    __syncthreads();
    if (t < 4) {
        float sm = 0.f;
        for (int i = 0; i < 64; ++i) sm += red64[t][i];
        dn[t] = 1.f / sm;
    }
    __syncthreads();
    {   // u_h = sum_k p_h[k] * X_k  (X read column-coalesced)
        int q4 = t >> 7, d = t & 127;
        float a0 = 0.f, a1 = 0.f, a2 = 0.f, a3 = 0.f;
        const float* xc = X + ((long)b*512 + q4*128)*128 + d;
        for (int kk = 0; kk < 128; ++kk) {
            float xv = xc[(long)kk*128];
            int k = q4*128 + kk;
            a0 += xv * l_sm[0][k];
            a1 += xv * l_sm[1][k];
            a2 += xv * l_sm[2][k];
            a3 += xv * l_sm[3][k];
        }
        part[q4][0][d] = a0; part[q4][1][d] = a1; part[q4][2][d] = a2; part[q4][3][d] = a3;
    }
    __syncthreads();
    {
        int h = t >> 7, d = t & 127;
        u_sm[h][d] = (part[0][h][d] + part[1][h][d] + part[2][h][d] + part[3][h][d]) * dn[h];
    }
    __syncthreads();
    {   // O[c] = qs[c] + u_{c>>5} @ Wv[:,c] + bv[c]
        int q4 = t >> 7, c = t & 127, h = c >> 5;
        float a = 0.f;
        #pragma unroll
        for (int j = 0; j < 32; ++j) {
            int k = q4*32 + j;
            a += u_sm[h][k] * Wv[k*128 + c];
        }
        red[q4][c] = a;
    }
    __syncthreads();
    if (t < 128) Ovec[t] = qs[t] + red[0][t] + red[1][t] + red[2][t] + red[3][t] + bv[t];
    __syncthreads();
    float mv = matvec_qs(Wo, Ovec, red, t);
    if (t < 128) Hsm[t] = Ovec[t] + fmaxf(mv + bo[t], 0.f);
    __syncthreads();
    float mv2 = matvec_qs(Wv1, Hsm, red, t);
    if (t < 128) vpod[b*128 + t] = mv2 + bv1[t];
}

// ---------------- PMA (logit-trick) + SAB + SAB + dec + prototypes ------------------------------
__global__ __launch_bounds__(512) void attn_pma_kernel(
    const float* __restrict__ X, const float* __restrict__ qp,
    const float* __restrict__ wkh, const float* __restrict__ ckh,
    const float* __restrict__ mab_Wq, const float* __restrict__ mab_bq,
    const float* __restrict__ mab_Wv, const float* __restrict__ mab_bv,
    const float* __restrict__ mab_Wo, const float* __restrict__ mab_bo,
    const float* __restrict__ dec_W, const float* __restrict__ dec_b,
    const float* __restrict__ protos, float* __restrict__ out)
{
    __shared__ float l_sm[4][512];
    __shared__ float part[4][4][128];
    __shared__ float wks[4][128];
    __shared__ float u_sm[4][128];
    __shared__ float red[4][128];
    __shared__ float red64[4][64];
    __shared__ float mx[4], dn[4];
    __shared__ float qs[128], Ovec[128], S1[128], S2[128];
    int b = blockIdx.x, t = threadIdx.x;
    if (t < 128) qs[t] = qp[t];
    wks[t >> 7][t & 127] = wkh[t];
    __syncthreads();
    const float scale = 0.088388347648318447f;
    float ck0 = ckh[0], ck1 = ckh[1], ck2 = ckh[2], ck3 = ckh[3];
    {
        const float* xr = X + ((long)b*512 + t)*128;
        float l[4] = {0.f, 0.f, 0.f, 0.f};
        for (int d4 = 0; d4 < 128; d4 += 4) {
            float4 xv = *(const float4*)&xr[d4];
            #pragma unroll
            for (int h = 0; h < 4; ++h)
                l[h] += xv.x*wks[h][d4] + xv.y*wks[h][d4+1]
                      + xv.z*wks[h][d4+2] + xv.w*wks[h][d4+3];
        }
        l_sm[0][t] = (l[0] + ck0) * scale;
        l_sm[1][t] = (l[1] + ck1) * scale;
        l_sm[2][t] = (l[2] + ck2) * scale;
        l_sm[3][t] = (l[3] + ck3) * scale;
    }
    __syncthreads();
    if (t < 256) {
        int h = t >> 6, i = t & 63;
        float m = -1e30f;
        #pragma unroll
        for (int j = 0; j < 8; ++j) m = fmaxf(m, l_sm[h][i + 64*j]);
        red64[h][i] = m;
    }
    __syncthreads();
    if (t < 4) {
        float m = -1e30f;
        for (int i = 0; i < 64; ++i) m = fmaxf(m, red64[t][i]);
        mx[t] = m;
    }
    __syncthreads();
    #pragma unroll
    for (int h = 0; h < 4; ++h) l_sm[h][t] = __expf(l_sm[h][t] - mx[h]);
    __syncthreads();
    if (t < 256) {
        int h = t >> 6, i = t & 63;
        float ssum = 0.f;
        #pragma unroll
        for (int j = 0; j < 8; ++j) ssum += l_sm[h][i + 64*j];
        red64[h][i] = ssum;
    }
    __syncthreads();
    if (t < 4) {
        float sm = 0.f;
        for (int i = 0; i < 64; ++i) sm += red64[t][i];
        dn[t] = 1.f / sm;
    }
    __syncthreads();
    {
        int q4 = t >> 7, d = t & 127;
        float a0 = 0.f, a1 = 0.f, a2 = 0.f, a3 = 0.f;
        const float* xc = X + ((long)b*512 + q4*128)*128 + d;
        for (int kk = 0; kk < 128; ++kk) {
            float xv = xc[(long)kk*128];
            int k = q4*128 + kk;
            a0 += xv * l_sm[0][k];
            a1 += xv * l_sm[1][k];
            a2 += xv * l_sm[2][k];
            a3 += xv * l_sm[3][k];
        }
        part[q4][0][d] = a0; part[q4][1][d] = a1; part[q4][2][d] = a2; part[q4][3][d] = a3;
    }
    __syncthreads();
    {
        int h = t >> 7, d = t & 127;
        u_sm[h][d] = (part[0][h][d] + part[1][h][d] + part[2][h][d] + part[3][h][d]) * dn[h];
    }
    __syncthreads();
    {
        int q4 = t >> 7, c = t & 127, h = c >> 5;
        float a = 0.f;
        #pragma unroll
        for (int j = 0; j < 32; ++j) {
            int k = q4*32 + j;
            a += u_sm[h][k] * (mab_Wv + 4*16384)[k*128 + c];
        }
        red[q4][c] = a;
    }
    __syncthreads();
    if (t < 128) Ovec[t] = qs[t] + red[0][t] + red[1][t] + red[2][t] + red[3][t]
                         + mab_bv[4*128 + t];
    __syncthreads();
    // X5 = O + relu(O@Wo4 + bo4)
    float mv = matvec_qs(mab_Wo + 4*16384, Ovec, red, t);
    if (t < 128) S1[t] = Ovec[t] + fmaxf(mv + mab_bo[4*128 + t], 0.f);
    __syncthreads();
    // SAB (mab5)
    float q5 = matvec_qs(mab_Wq + 5*16384, S1, red, t);
    float v5 = matvec_qs(mab_Wv + 5*16384, S1, red, t);
    if (t < 128) S2[t] = q5 + mab_bq[5*128 + t] + v5 + mab_bv[5*128 + t];
    __syncthreads();
    float m5 = matvec_qs(mab_Wo + 5*16384, S2, red, t);
    if (t < 128) S1[t] = S2[t] + fmaxf(m5 + mab_bo[5*128 + t], 0.f);
    __syncthreads();
    // SAB (mab6)
    float q6 = matvec_qs(mab_Wq + 6*16384, S1, red, t);
    float v6 = matvec_qs(mab_Wv + 6*16384, S1, red, t);
    if (t < 128) S2[t] = q6 + mab_bq[6*128 + t] + v6 + mab_bv[6*128 + t];
    __syncthreads();
    float m6 = matvec_qs(mab_Wo + 6*16384, S2, red, t);
    if (t < 128) S1[t] = S2[t] + fmaxf(m6 + mab_bo[6*128 + t], 0.f);
    __syncthreads();
    // dec linear
    float y = matvec_qs(dec_W, S1, red, t);
    if (t < 128) out[b*768 + t] = y + dec_b[t];
    // prototypes -> rows 1..5
    {
        int p = t >> 7, c = t & 127;
        out[b*768 + (1 + p)*128 + c] = protos[p*128 + c];
        if (t < 128) out[b*768 + 640 + t] = protos[512 + t];
    }
}

extern "C" void kernel_launch(void* const* d_in, const int* in_sizes, int n_in,
                              void* d_out, int out_size, void* d_ws, size_t ws_size,
                              hipStream_t stream)
{
    (void)in_sizes; (void)n_in; (void)out_size; (void)ws_size;
    const int*   node_ids  = (const int*)d_in[0];
    const int*   edge_idx  = (const int*)d_in[1];
    const float* node_embed= (const float*)d_in[3];
    const float* lin_W     = (const float*)d_in[4];
    const float* lin_b     = (const float*)d_in[5];
    const float* gat_W     = (const float*)d_in[6];
    const float* att_src   = (const float*)d_in[7];
    const float* att_dst   = (const float*)d_in[8];
    const float* gat_bias  = (const float*)d_in[9];
    const float* mab_Wq    = (const float*)d_in[10];
    const float* mab_bq    = (const float*)d_in[11];
    const float* mab_Wk    = (const float*)d_in[12];
    const float* mab_bk    = (const float*)d_in[13];
    const float* mab_Wv    = (const float*)d_in[14];
    const float* mab_bv    = (const float*)d_in[15];
    const float* mab_Wo    = (const float*)d_in[16];
    const float* mab_bo    = (const float*)d_in[17];
    const float* isab_I    = (const float*)d_in[18];
    const float* pma_S     = (const float*)d_in[19];
    const float* dec_W     = (const float*)d_in[20];
    const float* dec_b     = (const float*)d_in[21];
    const float* protos    = (const float*)d_in[22];

    float* ws    = (float*)d_ws;
    float* xw    = ws + OFF_XW;
    float* X     = ws + OFF_X;
    float* acc   = ws + OFF_ACC;
    float* a_s   = ws + OFF_AS;
    float* a_d   = ws + OFF_AD;
    float* Wc    = ws + OFF_WC;
    float* bc    = ws + OFF_BC;
    float* qp    = ws + OFF_QP;
    float* wkh   = ws + OFF_WKH;
    float* ckh   = ws + OFF_CKH;
    float* vpod  = ws + OFF_VPOD;
    int*   mask  = (int*)(ws + OFF_MASK);
    int*   deg   = (int*)(ws + OFF_DEG);
    int*   fill  = (int*)(ws + OFF_FILL);
    int*   cnt   = (int*)(ws + OFF_CNT);
    int*   npair = cnt + 1;
    int*   map   = (int*)(ws + OFF_MAP);
    int*   inv   = (int*)(ws + OFF_INV);
    int*   rowp  = (int*)(ws + OFF_ROWPTR);
    int2*  pairs = (int2*)(ws + OFF_PAIRS);
    int*   colx  = (int*)(ws + OFF_COL);
    float* out   = (float*)d_out;

    hipMemsetAsync(ws + OFF_MASK, 0, ZERO_BYTES, stream);

    prep_kernel<<<66, 256, 0, stream>>>(lin_W, lin_b, gat_W, mab_Wq, mab_bq, isab_I, pma_S,
                                        Wc, bc, qp);
    prep2_kernel<<<7, 256, 0, stream>>>(mab_Wk, mab_bk, qp, wkh, ckh);
    gemm0_kernel<<<N_NODES/16, 256, 0, stream>>>(node_embed, Wc, bc, xw);
    avec_kernel<<<N_NODES/4, 256, 0, stream>>>(xw, att_src, att_dst, a_s, a_d);
    maskset_kernel<<<(NROWS + 255)/256, 256, 0, stream>>>(node_ids, mask);
    assign_kernel<<<(N_NODES + 255)/256, 256, 0, stream>>>(mask, map, inv, cnt);
    pass1_kernel<<<(N_ITEMS + 255)/256, 256, 0, stream>>>(edge_idx, map, deg, npair, pairs);
    scan_kernel<<<1, 256, 0, stream>>>(deg, rowp);
    pass2_kernel<<<(N_ITEMS + 255)/256, 256, 0, stream>>>(pairs, npair, rowp, fill, colx);
    agg_kernel<<<NROWS/4, 256, 0, stream>>>(rowp, colx, inv, cnt, a_s, a_d, xw, acc);
    gather_kernel<<<NROWS/4, 256, 0, stream>>>(node_ids, map, acc, gat_bias, X);

    for (int i = 0; i < 2; ++i) {
        int o = 2*i + 1;
        attn_even_kernel<<<16, 512, 0, stream>>>(X, qp + i*128, wkh + i*512, ckh + i*4,
                                                 mab_Wv + (2*i)*16384, mab_bv + (2*i)*128,
                                                 mab_Wo + (2*i)*16384, mab_bo + (2*i)*128,
                                                 mab_Wv + o*16384, mab_bv + o*128,
                                                 vpod);
        gemm_odd_kernel<<<NROWS/16, 256, 0, stream>>>(X, mab_Wq + o*16384, mab_bq + o*128,
                                                      vpod, mab_Wo + o*16384, mab_bo + o*128,
                                                      X);
    }
    attn_pma_kernel<<<16, 512, 0, stream>>>(X, qp + 256, wkh + 1024, ckh + 8,
                                            mab_Wq, mab_bq, mab_Wv, mab_bv, mab_Wo, mab_bo,
                                            dec_W, dec_b, protos, out);
}

// Round 4
// 318.550 us; speedup vs baseline: 1.4181x; 1.4181x over previous
//
#include <hip/hip_runtime.h>
#include <math.h>

#define N_NODES 50000
#define N_EDGES 600000
#define BATCH 16
#define SEQ 512
#define NROWS (BATCH*SEQ)   // 8192
#define N_ITEMS (N_EDGES + N_NODES)

// ---- workspace layout (float offsets) ----
#define OFF_XW     0L
#define OFF_X      (OFF_XW + 6400000L)
#define OFF_ACC    (OFF_X + 1048576L)
#define OFF_AS     (OFF_ACC + 1048576L)
#define OFF_AD     (OFF_AS + 50000L)
#define OFF_WC     (OFF_AD + 50000L)
#define OFF_BC     (OFF_WC + 16384L)
#define OFF_QP     (OFF_BC + 128L)
#define OFF_WKH    (OFF_QP + 384L)
#define OFF_CKH    (OFF_WKH + 1536L)
#define OFF_VPOD   (OFF_CKH + 16L)
// ---- zeroed-every-launch block (one memset) ----
#define OFF_MASK   (OFF_VPOD + 2048L)
#define OFF_DEG    (OFF_MASK + 50000L)
#define OFF_FILL   (OFF_DEG + 8192L)
#define OFF_CNT    (OFF_FILL + 8192L)          // [cnt, pad, pad, pad]
#define ZERO_BYTES ((50000L + 8192L + 8192L + 4L) * 4L)
// ---- end zeroed block ----
#define OFF_MAP    (OFF_CNT + 4L)
#define OFF_INV    (OFF_MAP + 50000L)
#define OFF_ROWPTR (OFF_INV + 8192L)
#define OFF_COL    (OFF_ROWPTR + 8194L)

// ---------------- prep: Wc = lin_W @ gat_W, bc = lin_b @ gat_W, qp for mabs 0/2/4 ----------------
__global__ __launch_bounds__(256) void prep_kernel(
    const float* __restrict__ lin_W, const float* __restrict__ lin_b,
    const float* __restrict__ gat_W,
    const float* __restrict__ mab_Wq, const float* __restrict__ mab_bq,
    const float* __restrict__ isab_I, const float* __restrict__ pma_S,
    float* __restrict__ Wc, float* __restrict__ bc, float* __restrict__ qp)
{
    int t = blockIdx.x * 256 + threadIdx.x;
    if (t < 16384) {
        int i = t >> 7, j = t & 127;
        float s = 0.f;
        for (int k = 0; k < 128; ++k) s += lin_W[i*128 + k] * gat_W[k*128 + j];
        Wc[t] = s;
    } else if (t < 16512) {
        int j = t - 16384;
        float s = 0.f;
        for (int k = 0; k < 128; ++k) s += lin_b[k] * gat_W[k*128 + j];
        bc[j] = s;
    } else if (t < 16896) {
        int u = t - 16512;
        int m = u >> 7, c = u & 127;
        int mi = m * 2;   // mab index 0, 2, 4
        const float* vec = (m == 0) ? isab_I : (m == 1 ? isab_I + 128 : pma_S);
        float s = mab_bq[mi*128 + c];
        for (int k = 0; k < 128; ++k) s += vec[k] * mab_Wq[mi*16384 + k*128 + c];
        qp[u] = s;
    }
}

// ---------------- prep2: head logit vectors wk_h = Wk[:,h-slice] @ qp_h, ck_h = bk_h . qp_h ------
__global__ __launch_bounds__(256) void prep2_kernel(
    const float* __restrict__ mab_Wk, const float* __restrict__ mab_bk,
    const float* __restrict__ qp, float* __restrict__ wkh, float* __restrict__ ckh)
{
    int t = blockIdx.x * 256 + threadIdx.x;
    if (t < 1536) {
        int m = t >> 9;           // 0..2 -> mab 0,2,4
        int h = (t >> 7) & 3;
        int j = t & 127;
        int mi = m * 2;
        const float* Wk = mab_Wk + mi*16384 + j*128 + h*32;
        const float* q  = qp + m*128 + h*32;
        float s = 0.f;
        #pragma unroll
        for (int d = 0; d < 32; ++d) s += Wk[d] * q[d];
        wkh[t] = s;
    } else if (t < 1548) {
        int u = t - 1536;         // m*4 + h
        int m = u >> 2, h = u & 3;
        int mi = m * 2;
        const float* bk = mab_bk + mi*128 + h*32;
        const float* q  = qp + m*128 + h*32;
        float s = 0.f;
        #pragma unroll
        for (int d = 0; d < 32; ++d) s += bk[d] * q[d];
        ckh[u] = s;
    }
}

// ---------------- gemm0: xw = node_embed[:N] @ Wc + bc -----------------------------------------
__global__ __launch_bounds__(256) void gemm0_kernel(
    const float* __restrict__ Xin, const float* __restrict__ W1,
    const float* __restrict__ b1, float* __restrict__ out1)
{
    __shared__ float Xs[16][128];
    int t = threadIdx.x;
    long row0 = (long)blockIdx.x * 16;
    #pragma unroll
    for (int i = 0; i < 8; ++i) {
        int idx = i*256 + t;
        int r = idx >> 7, k = idx & 127;
        Xs[r][k] = Xin[(row0 + r)*128 + k];
    }
    __syncthreads();
    int c  = t & 127;
    int hh = t >> 7;
    float acc1[8];
    #pragma unroll
    for (int r = 0; r < 8; ++r) acc1[r] = 0.f;
    for (int k4 = 0; k4 < 128; k4 += 4) {
        float xv[8][4];
        #pragma unroll
        for (int r = 0; r < 8; ++r) {
            float4 tmp = *(const float4*)&Xs[hh*8 + r][k4];
            xv[r][0] = tmp.x; xv[r][1] = tmp.y; xv[r][2] = tmp.z; xv[r][3] = tmp.w;
        }
        #pragma unroll
        for (int kk = 0; kk < 4; ++kk) {
            float w1 = W1[(k4 + kk)*128 + c];
            #pragma unroll
            for (int r = 0; r < 8; ++r) acc1[r] += xv[r][kk] * w1;
        }
    }
    float bb = b1[c];
    #pragma unroll
    for (int r = 0; r < 8; ++r) out1[(row0 + hh*8 + r)*128 + c] = acc1[r] + bb;
}

// ---------------- fused odd-MAB: Xout = O1 + relu(O1@Wo+bo), O1 = X@Wq+bq+vpod[b] ---------------
__global__ __launch_bounds__(256) void gemm_odd_kernel(
    const float* __restrict__ X, const float* __restrict__ Wq,
    const float* __restrict__ bq, const float* __restrict__ vpod,
    const float* __restrict__ Wo, const float* __restrict__ bo,
    float* __restrict__ Xout)
{
    __shared__ float Xs[16][128];
    __shared__ float O1[16][128];
    int t = threadIdx.x;
    long row0 = (long)blockIdx.x * 16;
    int bidx = (int)(row0 >> 9);
    #pragma unroll
    for (int i = 0; i < 8; ++i) {
        int idx = i*256 + t;
        int r = idx >> 7, k = idx & 127;
        Xs[r][k] = X[(row0 + r)*128 + k];
    }
    __syncthreads();
    int c  = t & 127;
    int hh = t >> 7;
    float acc[8];
    #pragma unroll
    for (int r = 0; r < 8; ++r) acc[r] = 0.f;
    for (int k4 = 0; k4 < 128; k4 += 4) {
        float xv[8][4];
        #pragma unroll
        for (int r = 0; r < 8; ++r) {
            float4 tmp = *(const float4*)&Xs[hh*8 + r][k4];
            xv[r][0] = tmp.x; xv[r][1] = tmp.y; xv[r][2] = tmp.z; xv[r][3] = tmp.w;
        }
        #pragma unroll
        for (int kk = 0; kk < 4; ++kk) {
            float w = Wq[(k4 + kk)*128 + c];
            #pragma unroll
            for (int r = 0; r < 8; ++r) acc[r] += xv[r][kk] * w;
        }
    }
    float bb = bq[c] + vpod[bidx*128 + c];
    #pragma unroll
    for (int r = 0; r < 8; ++r) O1[hh*8 + r][c] = acc[r] + bb;
    __syncthreads();
    #pragma unroll
    for (int r = 0; r < 8; ++r) acc[r] = 0.f;
    for (int k4 = 0; k4 < 128; k4 += 4) {
        float xv[8][4];
        #pragma unroll
        for (int r = 0; r < 8; ++r) {
            float4 tmp = *(const float4*)&O1[hh*8 + r][k4];
            xv[r][0] = tmp.x; xv[r][1] = tmp.y; xv[r][2] = tmp.z; xv[r][3] = tmp.w;
        }
        #pragma unroll
        for (int kk = 0; kk < 4; ++kk) {
            float w = Wo[(k4 + kk)*128 + c];
            #pragma unroll
            for (int r = 0; r < 8; ++r) acc[r] += xv[r][kk] * w;
        }
    }
    float bb2 = bo[c];
    #pragma unroll
    for (int r = 0; r < 8; ++r)
        Xout[(row0 + hh*8 + r)*128 + c] = O1[hh*8 + r][c] + fmaxf(acc[r] + bb2, 0.f);
}

// ---------------- per-node attention scalars a_s, a_d ----------------
__global__ __launch_bounds__(256) void avec_kernel(
    const float* __restrict__ xw, const float* __restrict__ att_src,
    const float* __restrict__ att_dst, float* __restrict__ a_s, float* __restrict__ a_d)
{
    int w = threadIdx.x >> 6, lane = threadIdx.x & 63;
    long row = (long)blockIdx.x * 4 + w;
    const float* xr = xw + row*128 + lane*2;
    float x0 = xr[0], x1 = xr[1];
    float s = x0*att_src[lane*2] + x1*att_src[lane*2 + 1];
    float d = x0*att_dst[lane*2] + x1*att_dst[lane*2 + 1];
    #pragma unroll
    for (int off = 32; off > 0; off >>= 1) {
        s += __shfl_down(s, off);
        d += __shfl_down(d, off);
    }
    if (lane == 0) { a_s[row] = s; a_d[row] = d; }
}

// ---------------- mark needed destination nodes ----------------
__global__ void maskset_kernel(const int* __restrict__ node_ids, int* __restrict__ mask)
{
    int i = blockIdx.x*256 + threadIdx.x;
    if (i < NROWS) mask[node_ids[i]] = 1;
}

// ---------------- assign compact indices + inverse map (one atomic per BLOCK) -------------------
__global__ __launch_bounds__(256) void assign_kernel(
    const int* __restrict__ mask, int* __restrict__ map,
    int* __restrict__ inv, int* __restrict__ counter)
{
    __shared__ int wbase[4];
    int i = blockIdx.x*256 + threadIdx.x;
    bool act = (i < N_NODES) && mask[i];
    unsigned long long m = __ballot(act);
    int lane = threadIdx.x & 63;
    int w = threadIdx.x >> 6;
    if (lane == 0) wbase[w] = __popcll(m);
    __syncthreads();
    if (threadIdx.x == 0) {
        int tot = wbase[0] + wbase[1] + wbase[2] + wbase[3];
        int base = atomicAdd(counter, tot);
        int r = base;
        #pragma unroll
        for (int j = 0; j < 4; ++j) { int cj = wbase[j]; wbase[j] = r; r += cj; }
    }
    __syncthreads();
    if (i < N_NODES) {
        int c = -1;
        if (act) {
            c = wbase[w] + __popcll(m & ((1ull << lane) - 1ull));
            inv[c] = i;
        }
        map[i] = c;
    }
}

// ---------------- pass1: per-dest degree count (distributed atomics only) -----------------------
__global__ __launch_bounds__(256) void pass1_kernel(
    const int* __restrict__ edge_idx, const int* __restrict__ map,
    int* __restrict__ deg)
{
    int i = blockIdx.x*256 + threadIdx.x;
    if (i >= N_ITEMS) return;
    int dd = (i < N_EDGES) ? edge_idx[N_EDGES + i] : i - N_EDGES;
    int c = map[dd];
    if (c >= 0) atomicAdd(&deg[c], 1);
}

// ---------------- exclusive scan of deg[0..8191] -> rowptr[0..8192] (single block) --------------
__global__ __launch_bounds__(256) void scan_kernel(const int* __restrict__ deg,
                                                   int* __restrict__ rowptr)
{
    __shared__ int part[256];
    __shared__ int pref[256];
    int t = threadIdx.x;
    int base = t * 32;
    int s = 0;
    #pragma unroll
    for (int j = 0; j < 32; ++j) s += deg[base + j];
    part[t] = s;
    __syncthreads();
    if (t == 0) {
        int run = 0;
        for (int i = 0; i < 256; ++i) { pref[i] = run; run += part[i]; }
    }
    __syncthreads();
    int run = pref[t];
    #pragma unroll
    for (int j = 0; j < 32; ++j) { rowptr[base + j] = run; run += deg[base + j]; }
    if (t == 255) rowptr[8192] = run;
}

// ---------------- pass2: fill CSR column lists (re-reads edges, distributed atomics) ------------
__global__ __launch_bounds__(256) void pass2_kernel(
    const int* __restrict__ edge_idx, const int* __restrict__ map,
    const int* __restrict__ rowptr, int* __restrict__ fill,
    int* __restrict__ colx)
{
    int i = blockIdx.x*256 + threadIdx.x;
    if (i >= N_ITEMS) return;
    int s, dd;
    if (i < N_EDGES) { s = edge_idx[i]; dd = edge_idx[N_EDGES + i]; }
    else             { s = dd = i - N_EDGES; }
    int c = map[dd];
    if (c < 0) return;
    int pos = rowptr[c] + atomicAdd(&fill[c], 1);
    colx[pos] = s;
}

// ---------------- aggregate: one wave per masked destination, zero f32 atomics ------------------
__global__ __launch_bounds__(256) void agg_kernel(
    const int* __restrict__ rowptr, const int* __restrict__ colx,
    const int* __restrict__ inv, const int* __restrict__ cnt,
    const float* __restrict__ a_s, const float* __restrict__ a_d,
    const float* __restrict__ xw, float* __restrict__ acc)
{
    int c = blockIdx.x*4 + (threadIdx.x >> 6);
    int lane = threadIdx.x & 63;
    if (c >= *cnt) return;
    int dd = inv[c];
    float ad = a_d[dd];
    int beg = rowptr[c], end = rowptr[c + 1];
    float s0 = 0.f, s1 = 0.f, den = 0.f;
    for (int j = beg; j < end; ++j) {
        int s = colx[j];
        float e = a_s[s] + ad;
        e = (e > 0.f) ? e : 0.2f * e;
        float ex = __expf(e);
        den += ex;
        float2 v = *(const float2*)(xw + (long)s*128 + lane*2);
        s0 += ex * v.x;
        s1 += ex * v.y;
    }
    float inv_d = 1.f / den;
    float* o = acc + (long)c*128 + lane*2;
    o[0] = s0 * inv_d;
    o[1] = s1 * inv_d;
}

// ---------------- gather sampled node rows: + bias ----------------
__global__ __launch_bounds__(256) void gather_kernel(
    const int* __restrict__ node_ids, const int* __restrict__ map,
    const float* __restrict__ acc, const float* __restrict__ gat_bias,
    float* __restrict__ X)
{
    int w = threadIdx.x >> 6, lane = threadIdx.x & 63;
    int j = blockIdx.x*4 + w;
    int c = map[node_ids[j]];
    const float2 v = *(const float2*)(acc + (long)c*128 + lane*2);
    float* o = X + (long)j*128 + lane*2;
    o[0] = v.x + gat_bias[lane*2];
    o[1] = v.y + gat_bias[lane*2 + 1];
}

// ---------------- 128x128 matvec with 512 threads (4-way split-K + LDS reduce) -----------------
__device__ __forceinline__ float matvec_qs(
    const float* __restrict__ W, const float* xs, float (*red)[128], int t)
{
    int c = t & 127, q = t >> 7;
    float acc = 0.f;
    #pragma unroll
    for (int j = 0; j < 32; ++j) {
        int k = q*32 + j;
        acc += xs[k] * W[k*128 + c];
    }
    red[q][c] = acc;
    __syncthreads();
    float s = 0.f;
    if (t < 128) s = red[0][t] + red[1][t] + red[2][t] + red[3][t];
    __syncthreads();
    return s;
}

// ---------------- even MAB via logit-trick: no Kp/Vp materialization ----------------------------
__global__ __launch_bounds__(512) void attn_even_kernel(
    const float* __restrict__ X, const float* __restrict__ qp,
    const float* __restrict__ wkh, const float* __restrict__ ckh,
    const float* __restrict__ Wv, const float* __restrict__ bv,
    const float* __restrict__ Wo, const float* __restrict__ bo,
    const float* __restrict__ Wv1, const float* __restrict__ bv1,
    float* __restrict__ vpod)
{
    __shared__ float l_sm[4][512];
    __shared__ float part[4][4][128];
    __shared__ float wks[4][128];
    __shared__ float u_sm[4][128];
    __shared__ float red[4][128];
    __shared__ float red64[4][64];
    __shared__ float mx[4], dn[4];
    __shared__ float qs[128], Ovec[128], Hsm[128];
    int b = blockIdx.x, t = threadIdx.x;
    if (t < 128) qs[t] = qp[t];
    wks[t >> 7][t & 127] = wkh[t];
    __syncthreads();
    const float scale = 0.088388347648318447f;  // 1/sqrt(128)
    float ck0 = ckh[0], ck1 = ckh[1], ck2 = ckh[2], ck3 = ckh[3];
    {   // logits: l_h[k] = X_k . wk_h + ck_h
        const float* xr = X + ((long)b*512 + t)*128;
        float l[4] = {0.f, 0.f, 0.f, 0.f};
        for (int d4 = 0; d4 < 128; d4 += 4) {
            float4 xv = *(const float4*)&xr[d4];
            #pragma unroll
            for (int h = 0; h < 4; ++h)
                l[h] += xv.x*wks[h][d4] + xv.y*wks[h][d4+1]
                      + xv.z*wks[h][d4+2] + xv.w*wks[h][d4+3];
        }
        l_sm[0][t] = (l[0] + ck0) * scale;
        l_sm[1][t] = (l[1] + ck1) * scale;
        l_sm[2][t] = (l[2] + ck2) * scale;
        l_sm[3][t] = (l[3] + ck3) * scale;
    }
    __syncthreads();
    if (t < 256) {
        int h = t >> 6, i = t & 63;
        float m = -1e30f;
        #pragma unroll
        for (int j = 0; j < 8; ++j) m = fmaxf(m, l_sm[h][i + 64*j]);
        red64[h][i] = m;
    }
    __syncthreads();
    if (t < 4) {
        float m = -1e30f;
        for (int i = 0; i < 64; ++i) m = fmaxf(m, red64[t][i]);
        mx[t] = m;
    }
    __syncthreads();
    #pragma unroll
    for (int h = 0; h < 4; ++h) l_sm[h][t] = __expf(l_sm[h][t] - mx[h]);
    __syncthreads();
    if (t < 256) {
        int h = t >> 6, i = t & 63;
        float ssum = 0.f;
        #pragma unroll
        for (int j = 0; j < 8; ++j) ssum += l_sm[h][i + 64*j];
        red64[h][i] = ssum;
    }
    __syncthreads();
    if (t < 4) {
        float sm = 0.f;
        for (int i = 0; i < 64; ++i) sm += red64[t][i];
        dn[t] = 1.f / sm;
    }
    __syncthreads();
    {   // u_h = sum_k p_h[k] * X_k  (X read column-coalesced)
        int q4 = t >> 7, d = t & 127;
        float a0 = 0.f, a1 = 0.f, a2 = 0.f, a3 = 0.f;
        const float* xc = X + ((long)b*512 + q4*128)*128 + d;
        for (int kk = 0; kk < 128; ++kk) {
            float xv = xc[(long)kk*128];
            int k = q4*128 + kk;
            a0 += xv * l_sm[0][k];
            a1 += xv * l_sm[1][k];
            a2 += xv * l_sm[2][k];
            a3 += xv * l_sm[3][k];
        }
        part[q4][0][d] = a0; part[q4][1][d] = a1; part[q4][2][d] = a2; part[q4][3][d] = a3;
    }
    __syncthreads();
    {
        int h = t >> 7, d = t & 127;
        u_sm[h][d] = (part[0][h][d] + part[1][h][d] + part[2][h][d] + part[3][h][d]) * dn[h];
    }
    __syncthreads();
    {   // O[c] = qs[c] + u_{c>>5} @ Wv[:,c] + bv[c]
        int q4 = t >> 7, c = t & 127, h = c >> 5;
        float a = 0.f;
        #pragma unroll
        for (int j = 0; j < 32; ++j) {
            int k = q4*32 + j;
            a += u_sm[h][k] * Wv[k*128 + c];
        }
        red[q4][c] = a;
    }
    __syncthreads();
    if (t < 128) Ovec[t] = qs[t] + red[0][t] + red[1][t] + red[2][t] + red[3][t] + bv[t];
    __syncthreads();
    float mv = matvec_qs(Wo, Ovec, red, t);
    if (t < 128) Hsm[t] = Ovec[t] + fmaxf(mv + bo[t], 0.f);
    __syncthreads();
    float mv2 = matvec_qs(Wv1, Hsm, red, t);
    if (t < 128) vpod[b*128 + t] = mv2 + bv1[t];
}

// ---------------- PMA (logit-trick) + SAB + SAB + dec + prototypes ------------------------------
__global__ __launch_bounds__(512) void attn_pma_kernel(
    const float* __restrict__ X, const float* __restrict__ qp,
    const float* __restrict__ wkh, const float* __restrict__ ckh,
    const float* __restrict__ mab_Wq, const float* __restrict__ mab_bq,
    const float* __restrict__ mab_Wv, const float* __restrict__ mab_bv,
    const float* __restrict__ mab_Wo, const float* __restrict__ mab_bo,
    const float* __restrict__ dec_W, const float* __restrict__ dec_b,
    const float* __restrict__ protos, float* __restrict__ out)
{
    __shared__ float l_sm[4][512];
    __shared__ float part[4][4][128];
    __shared__ float wks[4][128];
    __shared__ float u_sm[4][128];
    __shared__ float red[4][128];
    __shared__ float red64[4][64];
    __shared__ float mx[4], dn[4];
    __shared__ float qs[128], Ovec[128], S1[128], S2[128];
    int b = blockIdx.x, t = threadIdx.x;
    if (t < 128) qs[t] = qp[t];
    wks[t >> 7][t & 127] = wkh[t];
    __syncthreads();
    const float scale = 0.088388347648318447f;
    float ck0 = ckh[0], ck1 = ckh[1], ck2 = ckh[2], ck3 = ckh[3];
    {
        const float* xr = X + ((long)b*512 + t)*128;
        float l[4] = {0.f, 0.f, 0.f, 0.f};
        for (int d4 = 0; d4 < 128; d4 += 4) {
            float4 xv = *(const float4*)&xr[d4];
            #pragma unroll
            for (int h = 0; h < 4; ++h)
                l[h] += xv.x*wks[h][d4] + xv.y*wks[h][d4+1]
                      + xv.z*wks[h][d4+2] + xv.w*wks[h][d4+3];
        }
        l_sm[0][t] = (l[0] + ck0) * scale;
        l_sm[1][t] = (l[1] + ck1) * scale;
        l_sm[2][t] = (l[2] + ck2) * scale;
        l_sm[3][t] = (l[3] + ck3) * scale;
    }
    __syncthreads();
    if (t < 256) {
        int h = t >> 6, i = t & 63;
        float m = -1e30f;
        #pragma unroll
        for (int j = 0; j < 8; ++j) m = fmaxf(m, l_sm[h][i + 64*j]);
        red64[h][i] = m;
    }
    __syncthreads();
    if (t < 4) {
        float m = -1e30f;
        for (int i = 0; i < 64; ++i) m = fmaxf(m, red64[t][i]);
        mx[t] = m;
    }
    __syncthreads();
    #pragma unroll
    for (int h = 0; h < 4; ++h) l_sm[h][t] = __expf(l_sm[h][t] - mx[h]);
    __syncthreads();
    if (t < 256) {
        int h = t >> 6, i = t & 63;
        float ssum = 0.f;
        #pragma unroll
        for (int j = 0; j < 8; ++j) ssum += l_sm[h][i + 64*j];
        red64[h][i] = ssum;
    }
    __syncthreads();
    if (t < 4) {
        float sm = 0.f;
        for (int i = 0; i < 64; ++i) sm += red64[t][i];
        dn[t] = 1.f / sm;
    }
    __syncthreads();
    {
        int q4 = t >> 7, d = t & 127;
        float a0 = 0.f, a1 = 0.f, a2 = 0.f, a3 = 0.f;
        const float* xc = X + ((long)b*512 + q4*128)*128 + d;
        for (int kk = 0; kk < 128; ++kk) {
            float xv = xc[(long)kk*128];
            int k = q4*128 + kk;
            a0 += xv * l_sm[0][k];
            a1 += xv * l_sm[1][k];
            a2 += xv * l_sm[2][k];
            a3 += xv * l_sm[3][k];
        }
        part[q4][0][d] = a0; part[q4][1][d] = a1; part[q4][2][d] = a2; part[q4][3][d] = a3;
    }
    __syncthreads();
    {
        int h = t >> 7, d = t & 127;
        u_sm[h][d] = (part[0][h][d] + part[1][h][d] + part[2][h][d] + part[3][h][d]) * dn[h];
    }
    __syncthreads();
    {
        int q4 = t >> 7, c = t & 127, h = c >> 5;
        float a = 0.f;
        #pragma unroll
        for (int j = 0; j < 32; ++j) {
            int k = q4*32 + j;
            a += u_sm[h][k] * (mab_Wv + 4*16384)[k*128 + c];
        }
        red[q4][c] = a;
    }
    __syncthreads();
    if (t < 128) Ovec[t] = qs[t] + red[0][t] + red[1][t] + red[2][t] + red[3][t]
                         + mab_bv[4*128 + t];
    __syncthreads();
    // X5 = O + relu(O@Wo4 + bo4)
    float mv = matvec_qs(mab_Wo + 4*16384, Ovec, red, t);
    if (t < 128) S1[t] = Ovec[t] + fmaxf(mv + mab_bo[4*128 + t], 0.f);
    __syncthreads();
    // SAB (mab5)
    float q5 = matvec_qs(mab_Wq + 5*16384, S1, red, t);
    float v5 = matvec_qs(mab_Wv + 5*16384, S1, red, t);
    if (t < 128) S2[t] = q5 + mab_bq[5*128 + t] + v5 + mab_bv[5*128 + t];
    __syncthreads();
    float m5 = matvec_qs(mab_Wo + 5*16384, S2, red, t);
    if (t < 128) S1[t] = S2[t] + fmaxf(m5 + mab_bo[5*128 + t], 0.f);
    __syncthreads();
    // SAB (mab6)
    float q6 = matvec_qs(mab_Wq + 6*16384, S1, red, t);
    float v6 = matvec_qs(mab_Wv + 6*16384, S1, red, t);
    if (t < 128) S2[t] = q6 + mab_bq[6*128 + t] + v6 + mab_bv[6*128 + t];
    __syncthreads();
    float m6 = matvec_qs(mab_Wo + 6*16384, S2, red, t);
    if (t < 128) S1[t] = S2[t] + fmaxf(m6 + mab_bo[6*128 + t], 0.f);
    __syncthreads();
    // dec linear
    float y = matvec_qs(dec_W, S1, red, t);
    if (t < 128) out[b*768 + t] = y + dec_b[t];
    // prototypes -> rows 1..5
    {
        int p = t >> 7, c = t & 127;
        out[b*768 + (1 + p)*128 + c] = protos[p*128 + c];
        if (t < 128) out[b*768 + 640 + t] = protos[512 + t];
    }
}

extern "C" void kernel_launch(void* const* d_in, const int* in_sizes, int n_in,
                              void* d_out, int out_size, void* d_ws, size_t ws_size,
                              hipStream_t stream)
{
    (void)in_sizes; (void)n_in; (void)out_size; (void)ws_size;
    const int*   node_ids  = (const int*)d_in[0];
    const int*   edge_idx  = (const int*)d_in[1];
    const float* node_embed= (const float*)d_in[3];
    const float* lin_W     = (const float*)d_in[4];
    const float* lin_b     = (const float*)d_in[5];
    const float* gat_W     = (const float*)d_in[6];
    const float* att_src   = (const float*)d_in[7];
    const float* att_dst   = (const float*)d_in[8];
    const float* gat_bias  = (const float*)d_in[9];
    const float* mab_Wq    = (const float*)d_in[10];
    const float* mab_bq    = (const float*)d_in[11];
    const float* mab_Wk    = (const float*)d_in[12];
    const float* mab_bk    = (const float*)d_in[13];
    const float* mab_Wv    = (const float*)d_in[14];
    const float* mab_bv    = (const float*)d_in[15];
    const float* mab_Wo    = (const float*)d_in[16];
    const float* mab_bo    = (const float*)d_in[17];
    const float* isab_I    = (const float*)d_in[18];
    const float* pma_S     = (const float*)d_in[19];
    const float* dec_W     = (const float*)d_in[20];
    const float* dec_b     = (const float*)d_in[21];
    const float* protos    = (const float*)d_in[22];

    float* ws    = (float*)d_ws;
    float* xw    = ws + OFF_XW;
    float* X     = ws + OFF_X;
    float* acc   = ws + OFF_ACC;
    float* a_s   = ws + OFF_AS;
    float* a_d   = ws + OFF_AD;
    float* Wc    = ws + OFF_WC;
    float* bc    = ws + OFF_BC;
    float* qp    = ws + OFF_QP;
    float* wkh   = ws + OFF_WKH;
    float* ckh   = ws + OFF_CKH;
    float* vpod  = ws + OFF_VPOD;
    int*   mask  = (int*)(ws + OFF_MASK);
    int*   deg   = (int*)(ws + OFF_DEG);
    int*   fill  = (int*)(ws + OFF_FILL);
    int*   cnt   = (int*)(ws + OFF_CNT);
    int*   map   = (int*)(ws + OFF_MAP);
    int*   inv   = (int*)(ws + OFF_INV);
    int*   rowp  = (int*)(ws + OFF_ROWPTR);
    int*   colx  = (int*)(ws + OFF_COL);
    float* out   = (float*)d_out;

    hipMemsetAsync(ws + OFF_MASK, 0, ZERO_BYTES, stream);

    prep_kernel<<<66, 256, 0, stream>>>(lin_W, lin_b, gat_W, mab_Wq, mab_bq, isab_I, pma_S,
                                        Wc, bc, qp);
    prep2_kernel<<<7, 256, 0, stream>>>(mab_Wk, mab_bk, qp, wkh, ckh);
    gemm0_kernel<<<N_NODES/16, 256, 0, stream>>>(node_embed, Wc, bc, xw);
    avec_kernel<<<N_NODES/4, 256, 0, stream>>>(xw, att_src, att_dst, a_s, a_d);
    maskset_kernel<<<(NROWS + 255)/256, 256, 0, stream>>>(node_ids, mask);
    assign_kernel<<<(N_NODES + 255)/256, 256, 0, stream>>>(mask, map, inv, cnt);
    pass1_kernel<<<(N_ITEMS + 255)/256, 256, 0, stream>>>(edge_idx, map, deg);
    scan_kernel<<<1, 256, 0, stream>>>(deg, rowp);
    pass2_kernel<<<(N_ITEMS + 255)/256, 256, 0, stream>>>(edge_idx, map, rowp, fill, colx);
    agg_kernel<<<NROWS/4, 256, 0, stream>>>(rowp, colx, inv, cnt, a_s, a_d, xw, acc);
    gather_kernel<<<NROWS/4, 256, 0, stream>>>(node_ids, map, acc, gat_bias, X);

    for (int i = 0; i < 2; ++i) {
        int o = 2*i + 1;
        attn_even_kernel<<<16, 512, 0, stream>>>(X, qp + i*128, wkh + i*512, ckh + i*4,
                                                 mab_Wv + (2*i)*16384, mab_bv + (2*i)*128,
                                                 mab_Wo + (2*i)*16384, mab_bo + (2*i)*128,
                                                 mab_Wv + o*16384, mab_bv + o*128,
                                                 vpod);
        gemm_odd_kernel<<<NROWS/16, 256, 0, stream>>>(X, mab_Wq + o*16384, mab_bq + o*128,
                                                      vpod, mab_Wo + o*16384, mab_bo + o*128,
                                                      X);
    }
    attn_pma_kernel<<<16, 512, 0, stream>>>(X, qp + 256, wkh + 1024, ckh + 8,
                                            mab_Wq, mab_bq, mab_Wv, mab_bv, mab_Wo, mab_bo,
                                            dec_W, dec_b, protos, out);
}

// Round 5
// 290.505 us; speedup vs baseline: 1.5550x; 1.0965x over previous
//
#include <hip/hip_runtime.h>
#include <math.h>

#define N_NODES 50000
#define N_EDGES 600000
#define BATCH 16
#define SEQ 512
#define NROWS (BATCH*SEQ)   // 8192
#define N_ITEMS (N_EDGES + N_NODES)

// ---- workspace layout (float offsets) ----
#define OFF_X      0L
#define OFF_ACC    1048576L
#define OFF_X2     2097152L
#define OFF_AS     3145728L
#define OFF_AD     3195728L
#define OFF_WC     3245728L
#define OFF_BC     3262112L
#define OFF_QP     3262240L
#define OFF_WKH    3262624L
#define OFF_CKH    3264160L
#define OFF_VAS    3264176L
#define OFF_VAD    3264304L
#define OFF_BFIN   3264432L
#define OFF_CSD    3264560L
#define OFF_VPOD   3264564L
// ---- zeroed-every-launch block (one memset) ----
#define OFF_MASK   3266612L
#define OFF_DEG    (OFF_MASK + 50000L)
#define OFF_FILL   (OFF_DEG + 8192L)
#define OFF_CNT    (OFF_FILL + 8192L)          // [cnt, pad, pad, pad]
#define ZERO_BYTES ((50000L + 8192L + 8192L + 4L) * 4L)
// ---- end zeroed block ----
#define OFF_MAP    (OFF_CNT + 4L)
#define OFF_INV    (OFF_MAP + 50000L)
#define OFF_ROWPTR (OFF_INV + 8192L)
#define OFF_COL    (OFF_ROWPTR + 8194L)

// ---------------- prep: Wc = lin_W @ gat_W, bc = lin_b @ gat_W, qp for mabs 0/2/4 ----------------
__global__ __launch_bounds__(256) void prep_kernel(
    const float* __restrict__ lin_W, const float* __restrict__ lin_b,
    const float* __restrict__ gat_W,
    const float* __restrict__ mab_Wq, const float* __restrict__ mab_bq,
    const float* __restrict__ isab_I, const float* __restrict__ pma_S,
    float* __restrict__ Wc, float* __restrict__ bc, float* __restrict__ qp)
{
    int t = blockIdx.x * 256 + threadIdx.x;
    if (t < 16384) {
        int i = t >> 7, j = t & 127;
        float s = 0.f;
        for (int k = 0; k < 128; ++k) s += lin_W[i*128 + k] * gat_W[k*128 + j];
        Wc[t] = s;
    } else if (t < 16512) {
        int j = t - 16384;
        float s = 0.f;
        for (int k = 0; k < 128; ++k) s += lin_b[k] * gat_W[k*128 + j];
        bc[j] = s;
    } else if (t < 16896) {
        int u = t - 16512;
        int m = u >> 7, c = u & 127;
        int mi = m * 2;   // mab index 0, 2, 4
        const float* vec = (m == 0) ? isab_I : (m == 1 ? isab_I + 128 : pma_S);
        float s = mab_bq[mi*128 + c];
        for (int k = 0; k < 128; ++k) s += vec[k] * mab_Wq[mi*16384 + k*128 + c];
        qp[u] = s;
    }
}

// ---------------- prep2: wkh/ckh (logit vectors), va_s/va_d (GAT attn vectors), bfin ------------
__global__ __launch_bounds__(256) void prep2_kernel(
    const float* __restrict__ mab_Wk, const float* __restrict__ mab_bk,
    const float* __restrict__ qp, const float* __restrict__ Wc,
    const float* __restrict__ bc, const float* __restrict__ att_src,
    const float* __restrict__ att_dst, const float* __restrict__ gat_bias,
    float* __restrict__ wkh, float* __restrict__ ckh,
    float* __restrict__ vas, float* __restrict__ vad,
    float* __restrict__ bfin, float* __restrict__ csd)
{
    int t = blockIdx.x * 256 + threadIdx.x;
    if (t < 1536) {
        int m = t >> 9;           // 0..2 -> mab 0,2,4
        int h = (t >> 7) & 3;
        int j = t & 127;
        int mi = m * 2;
        const float* Wk = mab_Wk + mi*16384 + j*128 + h*32;
        const float* q  = qp + m*128 + h*32;
        float s = 0.f;
        #pragma unroll
        for (int d = 0; d < 32; ++d) s += Wk[d] * q[d];
        wkh[t] = s;
    } else if (t < 1548) {
        int u = t - 1536;         // m*4 + h
        int m = u >> 2, h = u & 3;
        int mi = m * 2;
        const float* bk = mab_bk + mi*128 + h*32;
        const float* q  = qp + m*128 + h*32;
        float s = 0.f;
        #pragma unroll
        for (int d = 0; d < 32; ++d) s += bk[d] * q[d];
        ckh[u] = s;
    } else if (t < 1676) {
        int k = t - 1548;         // va_s[k] = Wc[k,:] . att_src
        float s = 0.f;
        for (int j = 0; j < 128; ++j) s += Wc[k*128 + j] * att_src[j];
        vas[k] = s;
    } else if (t < 1804) {
        int k = t - 1676;
        float s = 0.f;
        for (int j = 0; j < 128; ++j) s += Wc[k*128 + j] * att_dst[j];
        vad[k] = s;
    } else if (t < 1932) {
        int j = t - 1804;
        bfin[j] = bc[j] + gat_bias[j];
    } else if (t == 1932) {
        float s = 0.f;
        for (int j = 0; j < 128; ++j) s += bc[j] * att_src[j];
        csd[0] = s;
    } else if (t == 1933) {
        float s = 0.f;
        for (int j = 0; j < 128; ++j) s += bc[j] * att_dst[j];
        csd[1] = s;
    }
}

// ---------------- generic row-GEMM: out = Xin(rows x 128) @ W + b, 16 rows/block ----------------
__global__ __launch_bounds__(256) void gemm0_kernel(
    const float* __restrict__ Xin, const float* __restrict__ W1,
    const float* __restrict__ b1, float* __restrict__ out1)
{
    __shared__ float Xs[16][128];
    int t = threadIdx.x;
    long row0 = (long)blockIdx.x * 16;
    #pragma unroll
    for (int i = 0; i < 8; ++i) {
        int idx = i*256 + t;
        int r = idx >> 7, k = idx & 127;
        Xs[r][k] = Xin[(row0 + r)*128 + k];
    }
    __syncthreads();
    int c  = t & 127;
    int hh = t >> 7;
    float acc1[8];
    #pragma unroll
    for (int r = 0; r < 8; ++r) acc1[r] = 0.f;
    for (int k4 = 0; k4 < 128; k4 += 4) {
        float xv[8][4];
        #pragma unroll
        for (int r = 0; r < 8; ++r) {
            float4 tmp = *(const float4*)&Xs[hh*8 + r][k4];
            xv[r][0] = tmp.x; xv[r][1] = tmp.y; xv[r][2] = tmp.z; xv[r][3] = tmp.w;
        }
        #pragma unroll
        for (int kk = 0; kk < 4; ++kk) {
            float w1 = W1[(k4 + kk)*128 + c];
            #pragma unroll
            for (int r = 0; r < 8; ++r) acc1[r] += xv[r][kk] * w1;
        }
    }
    float bb = b1[c];
    #pragma unroll
    for (int r = 0; r < 8; ++r) out1[(row0 + hh*8 + r)*128 + c] = acc1[r] + bb;
}

// ---------------- fused odd-MAB: Xout = O1 + relu(O1@Wo+bo), O1 = X@Wq+bq+vpod[b] ---------------
__global__ __launch_bounds__(256) void gemm_odd_kernel(
    const float* __restrict__ X, const float* __restrict__ Wq,
    const float* __restrict__ bq, const float* __restrict__ vpod,
    const float* __restrict__ Wo, const float* __restrict__ bo,
    float* __restrict__ Xout)
{
    __shared__ float Xs[16][128];
    __shared__ float O1[16][128];
    int t = threadIdx.x;
    long row0 = (long)blockIdx.x * 16;
    int bidx = (int)(row0 >> 9);
    #pragma unroll
    for (int i = 0; i < 8; ++i) {
        int idx = i*256 + t;
        int r = idx >> 7, k = idx & 127;
        Xs[r][k] = X[(row0 + r)*128 + k];
    }
    __syncthreads();
    int c  = t & 127;
    int hh = t >> 7;
    float acc[8];
    #pragma unroll
    for (int r = 0; r < 8; ++r) acc[r] = 0.f;
    for (int k4 = 0; k4 < 128; k4 += 4) {
        float xv[8][4];
        #pragma unroll
        for (int r = 0; r < 8; ++r) {
            float4 tmp = *(const float4*)&Xs[hh*8 + r][k4];
            xv[r][0] = tmp.x; xv[r][1] = tmp.y; xv[r][2] = tmp.z; xv[r][3] = tmp.w;
        }
        #pragma unroll
        for (int kk = 0; kk < 4; ++kk) {
            float w = Wq[(k4 + kk)*128 + c];
            #pragma unroll
            for (int r = 0; r < 8; ++r) acc[r] += xv[r][kk] * w;
        }
    }
    float bb = bq[c] + vpod[bidx*128 + c];
    #pragma unroll
    for (int r = 0; r < 8; ++r) O1[hh*8 + r][c] = acc[r] + bb;
    __syncthreads();
    #pragma unroll
    for (int r = 0; r < 8; ++r) acc[r] = 0.f;
    for (int k4 = 0; k4 < 128; k4 += 4) {
        float xv[8][4];
        #pragma unroll
        for (int r = 0; r < 8; ++r) {
            float4 tmp = *(const float4*)&O1[hh*8 + r][k4];
            xv[r][0] = tmp.x; xv[r][1] = tmp.y; xv[r][2] = tmp.z; xv[r][3] = tmp.w;
        }
        #pragma unroll
        for (int kk = 0; kk < 4; ++kk) {
            float w = Wo[(k4 + kk)*128 + c];
            #pragma unroll
            for (int r = 0; r < 8; ++r) acc[r] += xv[r][kk] * w;
        }
    }
    float bb2 = bo[c];
    #pragma unroll
    for (int r = 0; r < 8; ++r)
        Xout[(row0 + hh*8 + r)*128 + c] = O1[hh*8 + r][c] + fmaxf(acc[r] + bb2, 0.f);
}

// ---------------- per-node attention scalars from embed: a = embed . va + c ---------------------
__global__ __launch_bounds__(256) void avec_kernel(
    const float* __restrict__ embed, const float* __restrict__ vas,
    const float* __restrict__ vad, const float* __restrict__ csd,
    float* __restrict__ a_s, float* __restrict__ a_d)
{
    int w = threadIdx.x >> 6, lane = threadIdx.x & 63;
    long row = (long)blockIdx.x * 4 + w;
    const float* xr = embed + row*128 + lane*2;
    float x0 = xr[0], x1 = xr[1];
    float s = x0*vas[lane*2] + x1*vas[lane*2 + 1];
    float d = x0*vad[lane*2] + x1*vad[lane*2 + 1];
    #pragma unroll
    for (int off = 32; off > 0; off >>= 1) {
        s += __shfl_down(s, off);
        d += __shfl_down(d, off);
    }
    if (lane == 0) { a_s[row] = s + csd[0]; a_d[row] = d + csd[1]; }
}

// ---------------- mark needed destination nodes ----------------
__global__ void maskset_kernel(const int* __restrict__ node_ids, int* __restrict__ mask)
{
    int i = blockIdx.x*256 + threadIdx.x;
    if (i < NROWS) mask[node_ids[i]] = 1;
}

// ---------------- assign compact indices + inverse map (one atomic per BLOCK) -------------------
__global__ __launch_bounds__(256) void assign_kernel(
    const int* __restrict__ mask, int* __restrict__ map,
    int* __restrict__ inv, int* __restrict__ counter)
{
    __shared__ int wbase[4];
    int i = blockIdx.x*256 + threadIdx.x;
    bool act = (i < N_NODES) && mask[i];
    unsigned long long m = __ballot(act);
    int lane = threadIdx.x & 63;
    int w = threadIdx.x >> 6;
    if (lane == 0) wbase[w] = __popcll(m);
    __syncthreads();
    if (threadIdx.x == 0) {
        int tot = wbase[0] + wbase[1] + wbase[2] + wbase[3];
        int base = atomicAdd(counter, tot);
        int r = base;
        #pragma unroll
        for (int j = 0; j < 4; ++j) { int cj = wbase[j]; wbase[j] = r; r += cj; }
    }
    __syncthreads();
    if (i < N_NODES) {
        int c = -1;
        if (act) {
            c = wbase[w] + __popcll(m & ((1ull << lane) - 1ull));
            inv[c] = i;
        }
        map[i] = c;
    }
}

// ---------------- pass1: per-dest degree count (distributed atomics only) -----------------------
__global__ __launch_bounds__(256) void pass1_kernel(
    const int* __restrict__ edge_idx, const int* __restrict__ map,
    int* __restrict__ deg)
{
    int i = blockIdx.x*256 + threadIdx.x;
    if (i >= N_ITEMS) return;
    int dd = (i < N_EDGES) ? edge_idx[N_EDGES + i] : i - N_EDGES;
    int c = map[dd];
    if (c >= 0) atomicAdd(&deg[c], 1);
}

// ---------------- exclusive scan of deg[0..8191] -> rowptr[0..8192] (single block) --------------
__global__ __launch_bounds__(256) void scan_kernel(const int* __restrict__ deg,
                                                   int* __restrict__ rowptr)
{
    __shared__ int part[256];
    __shared__ int pref[256];
    int t = threadIdx.x;
    int base = t * 32;
    int s = 0;
    #pragma unroll
    for (int j = 0; j < 32; ++j) s += deg[base + j];
    part[t] = s;
    __syncthreads();
    if (t == 0) {
        int run = 0;
        for (int i = 0; i < 256; ++i) { pref[i] = run; run += part[i]; }
    }
    __syncthreads();
    int run = pref[t];
    #pragma unroll
    for (int j = 0; j < 32; ++j) { rowptr[base + j] = run; run += deg[base + j]; }
    if (t == 255) rowptr[8192] = run;
}

// ---------------- pass2: fill CSR column lists (re-reads edges, distributed atomics) ------------
__global__ __launch_bounds__(256) void pass2_kernel(
    const int* __restrict__ edge_idx, const int* __restrict__ map,
    const int* __restrict__ rowptr, int* __restrict__ fill,
    int* __restrict__ colx)
{
    int i = blockIdx.x*256 + threadIdx.x;
    if (i >= N_ITEMS) return;
    int s, dd;
    if (i < N_EDGES) { s = edge_idx[i]; dd = edge_idx[N_EDGES + i]; }
    else             { s = dd = i - N_EDGES; }
    int c = map[dd];
    if (c < 0) return;
    int pos = rowptr[c] + atomicAdd(&fill[c], 1);
    colx[pos] = s;
}

// ---------------- aggregate IN EMBED SPACE: one wave per masked destination ---------------------
__global__ __launch_bounds__(256) void agg_kernel(
    const int* __restrict__ rowptr, const int* __restrict__ colx,
    const int* __restrict__ inv, const int* __restrict__ cnt,
    const float* __restrict__ a_s, const float* __restrict__ a_d,
    const float* __restrict__ embed, float* __restrict__ acc)
{
    int c = blockIdx.x*4 + (threadIdx.x >> 6);
    int lane = threadIdx.x & 63;
    if (c >= *cnt) return;
    int dd = inv[c];
    float ad = a_d[dd];
    int beg = rowptr[c], end = rowptr[c + 1];
    float s0 = 0.f, s1 = 0.f, den = 0.f;
    for (int j = beg; j < end; ++j) {
        int s = colx[j];
        float e = a_s[s] + ad;
        e = (e > 0.f) ? e : 0.2f * e;
        float ex = __expf(e);
        den += ex;
        float2 v = *(const float2*)(embed + (long)s*128 + lane*2);
        s0 += ex * v.x;
        s1 += ex * v.y;
    }
    float inv_d = 1.f / den;
    float* o = acc + (long)c*128 + lane*2;
    o[0] = s0 * inv_d;
    o[1] = s1 * inv_d;
}

// ---------------- gather sampled node rows ----------------
__global__ __launch_bounds__(256) void gather_kernel(
    const int* __restrict__ node_ids, const int* __restrict__ map,
    const float* __restrict__ X2, float* __restrict__ X)
{
    int w = threadIdx.x >> 6, lane = threadIdx.x & 63;
    int j = blockIdx.x*4 + w;
    int c = map[node_ids[j]];
    const float2 v = *(const float2*)(X2 + (long)c*128 + lane*2);
    *(float2*)(X + (long)j*128 + lane*2) = v;
}

// ---------------- 128x128 matvec with 512 threads (4-way split-K + LDS reduce) -----------------
__device__ __forceinline__ float matvec_qs(
    const float* __restrict__ W, const float* xs, float (*red)[128], int t)
{
    int c = t & 127, q = t >> 7;
    float acc = 0.f;
    #pragma unroll
    for (int j = 0; j < 32; ++j) {
        int k = q*32 + j;
        acc += xs[k] * W[k*128 + c];
    }
    red[q][c] = acc;
    __syncthreads();
    float s = 0.f;
    if (t < 128) s = red[0][t] + red[1][t] + red[2][t] + red[3][t];
    __syncthreads();
    return s;
}

// ---------------- even MAB via logit-trick: no Kp/Vp materialization ----------------------------
__global__ __launch_bounds__(512) void attn_even_kernel(
    const float* __restrict__ X, const float* __restrict__ qp,
    const float* __restrict__ wkh, const float* __restrict__ ckh,
    const float* __restrict__ Wv, const float* __restrict__ bv,
    const float* __restrict__ Wo, const float* __restrict__ bo,
    const float* __restrict__ Wv1, const float* __restrict__ bv1,
    float* __restrict__ vpod)
{
    __shared__ float l_sm[4][512];
    __shared__ float part[4][4][128];
    __shared__ float wks[4][128];
    __shared__ float u_sm[4][128];
    __shared__ float red[4][128];
    __shared__ float red64[4][64];
    __shared__ float mx[4], dn[4];
    __shared__ float qs[128], Ovec[128], Hsm[128];
    int b = blockIdx.x, t = threadIdx.x;
    if (t < 128) qs[t] = qp[t];
    wks[t >> 7][t & 127] = wkh[t];
    __syncthreads();
    const float scale = 0.088388347648318447f;  // 1/sqrt(128)
    float ck0 = ckh[0], ck1 = ckh[1], ck2 = ckh[2], ck3 = ckh[3];
    {   // logits: l_h[k] = X_k . wk_h + ck_h
        const float* xr = X + ((long)b*512 + t)*128;
        float l[4] = {0.f, 0.f, 0.f, 0.f};
        for (int d4 = 0; d4 < 128; d4 += 4) {
            float4 xv = *(const float4*)&xr[d4];
            #pragma unroll
            for (int h = 0; h < 4; ++h)
                l[h] += xv.x*wks[h][d4] + xv.y*wks[h][d4+1]
                      + xv.z*wks[h][d4+2] + xv.w*wks[h][d4+3];
        }
        l_sm[0][t] = (l[0] + ck0) * scale;
        l_sm[1][t] = (l[1] + ck1) * scale;
        l_sm[2][t] = (l[2] + ck2) * scale;
        l_sm[3][t] = (l[3] + ck3) * scale;
    }
    __syncthreads();
    if (t < 256) {
        int h = t >> 6, i = t & 63;
        float m = -1e30f;
        #pragma unroll
        for (int j = 0; j < 8; ++j) m = fmaxf(m, l_sm[h][i + 64*j]);
        red64[h][i] = m;
    }
    __syncthreads();
    if (t < 4) {
        float m = -1e30f;
        for (int i = 0; i < 64; ++i) m = fmaxf(m, red64[t][i]);
        mx[t] = m;
    }
    __syncthreads();
    #pragma unroll
    for (int h = 0; h < 4; ++h) l_sm[h][t] = __expf(l_sm[h][t] - mx[h]);
    __syncthreads();
    if (t < 256) {
        int h = t >> 6, i = t & 63;
        float ssum = 0.f;
        #pragma unroll
        for (int j = 0; j < 8; ++j) ssum += l_sm[h][i + 64*j];
        red64[h][i] = ssum;
    }
    __syncthreads();
    if (t < 4) {
        float sm = 0.f;
        for (int i = 0; i < 64; ++i) sm += red64[t][i];
        dn[t] = 1.f / sm;
    }
    __syncthreads();
    {   // u_h = sum_k p_h[k] * X_k  (X read column-coalesced)
        int q4 = t >> 7, d = t & 127;
        float a0 = 0.f, a1 = 0.f, a2 = 0.f, a3 = 0.f;
        const float* xc = X + ((long)b*512 + q4*128)*128 + d;
        for (int kk = 0; kk < 128; ++kk) {
            float xv = xc[(long)kk*128];
            int k = q4*128 + kk;
            a0 += xv * l_sm[0][k];
            a1 += xv * l_sm[1][k];
            a2 += xv * l_sm[2][k];
            a3 += xv * l_sm[3][k];
        }
        part[q4][0][d] = a0; part[q4][1][d] = a1; part[q4][2][d] = a2; part[q4][3][d] = a3;
    }
    __syncthreads();
    {
        int h = t >> 7, d = t & 127;
        u_sm[h][d] = (part[0][h][d] + part[1][h][d] + part[2][h][d] + part[3][h][d]) * dn[h];
    }
    __syncthreads();
    {   // O[c] = qs[c] + u_{c>>5} @ Wv[:,c] + bv[c]
        int q4 = t >> 7, c = t & 127, h = c >> 5;
        float a = 0.f;
        #pragma unroll
        for (int j = 0; j < 32; ++j) {
            int k = q4*32 + j;
            a += u_sm[h][k] * Wv[k*128 + c];
        }
        red[q4][c] = a;
    }
    __syncthreads();
    if (t < 128) Ovec[t] = qs[t] + red[0][t] + red[1][t] + red[2][t] + red[3][t] + bv[t];
    __syncthreads();
    float mv = matvec_qs(Wo, Ovec, red, t);
    if (t < 128) Hsm[t] = Ovec[t] + fmaxf(mv + bo[t], 0.f);
    __syncthreads();
    float mv2 = matvec_qs(Wv1, Hsm, red, t);
    if (t < 128) vpod[b*128 + t] = mv2 + bv1[t];
}

// ---------------- PMA (logit-trick) + SAB + SAB + dec + prototypes ------------------------------
__global__ __launch_bounds__(512) void attn_pma_kernel(
    const float* __restrict__ X, const float* __restrict__ qp,
    const float* __restrict__ wkh, const float* __restrict__ ckh,
    const float* __restrict__ mab_Wq, const float* __restrict__ mab_bq,
    const float* __restrict__ mab_Wv, const float* __restrict__ mab_bv,
    const float* __restrict__ mab_Wo, const float* __restrict__ mab_bo,
    const float* __restrict__ dec_W, const float* __restrict__ dec_b,
    const float* __restrict__ protos, float* __restrict__ out)
{
    __shared__ float l_sm[4][512];
    __shared__ float part[4][4][128];
    __shared__ float wks[4][128];
    __shared__ float u_sm[4][128];
    __shared__ float red[4][128];
    __shared__ float red64[4][64];
    __shared__ float mx[4], dn[4];
    __shared__ float qs[128], Ovec[128], S1[128], S2[128];
    int b = blockIdx.x, t = threadIdx.x;
    if (t < 128) qs[t] = qp[t];
    wks[t >> 7][t & 127] = wkh[t];
    __syncthreads();
    const float scale = 0.088388347648318447f;
    float ck0 = ckh[0], ck1 = ckh[1], ck2 = ckh[2], ck3 = ckh[3];
    {
        const float* xr = X + ((long)b*512 + t)*128;
        float l[4] = {0.f, 0.f, 0.f, 0.f};
        for (int d4 = 0; d4 < 128; d4 += 4) {
            float4 xv = *(const float4*)&xr[d4];
            #pragma unroll
            for (int h = 0; h < 4; ++h)
                l[h] += xv.x*wks[h][d4] + xv.y*wks[h][d4+1]
                      + xv.z*wks[h][d4+2] + xv.w*wks[h][d4+3];
        }
        l_sm[0][t] = (l[0] + ck0) * scale;
        l_sm[1][t] = (l[1] + ck1) * scale;
        l_sm[2][t] = (l[2] + ck2) * scale;
        l_sm[3][t] = (l[3] + ck3) * scale;
    }
    __syncthreads();
    if (t < 256) {
        int h = t >> 6, i = t & 63;
        float m = -1e30f;
        #pragma unroll
        for (int j = 0; j < 8; ++j) m = fmaxf(m, l_sm[h][i + 64*j]);
        red64[h][i] = m;
    }
    __syncthreads();
    if (t < 4) {
        float m = -1e30f;
        for (int i = 0; i < 64; ++i) m = fmaxf(m, red64[t][i]);
        mx[t] = m;
    }
    __syncthreads();
    #pragma unroll
    for (int h = 0; h < 4; ++h) l_sm[h][t] = __expf(l_sm[h][t] - mx[h]);
    __syncthreads();
    if (t < 256) {
        int h = t >> 6, i = t & 63;
        float ssum = 0.f;
        #pragma unroll
        for (int j = 0; j < 8; ++j) ssum += l_sm[h][i + 64*j];
        red64[h][i] = ssum;
    }
    __syncthreads();
    if (t < 4) {
        float sm = 0.f;
        for (int i = 0; i < 64; ++i) sm += red64[t][i];
        dn[t] = 1.f / sm;
    }
    __syncthreads();
    {
        int q4 = t >> 7, d = t & 127;
        float a0 = 0.f, a1 = 0.f, a2 = 0.f, a3 = 0.f;
        const float* xc = X + ((long)b*512 + q4*128)*128 + d;
        for (int kk = 0; kk < 128; ++kk) {
            float xv = xc[(long)kk*128];
            int k = q4*128 + kk;
            a0 += xv * l_sm[0][k];
            a1 += xv * l_sm[1][k];
            a2 += xv * l_sm[2][k];
            a3 += xv * l_sm[3][k];
        }
        part[q4][0][d] = a0; part[q4][1][d] = a1; part[q4][2][d] = a2; part[q4][3][d] = a3;
    }
    __syncthreads();
    {
        int h = t >> 7, d = t & 127;
        u_sm[h][d] = (part[0][h][d] + part[1][h][d] + part[2][h][d] + part[3][h][d]) * dn[h];
    }
    __syncthreads();
    {
        int q4 = t >> 7, c = t & 127, h = c >> 5;
        float a = 0.f;
        #pragma unroll
        for (int j = 0; j < 32; ++j) {
            int k = q4*32 + j;
            a += u_sm[h][k] * (mab_Wv + 4*16384)[k*128 + c];
        }
        red[q4][c] = a;
    }
    __syncthreads();
    if (t < 128) Ovec[t] = qs[t] + red[0][t] + red[1][t] + red[2][t] + red[3][t]
                         + mab_bv[4*128 + t];
    __syncthreads();
    // X5 = O + relu(O@Wo4 + bo4)
    float mv = matvec_qs(mab_Wo + 4*16384, Ovec, red, t);
    if (t < 128) S1[t] = Ovec[t] + fmaxf(mv + mab_bo[4*128 + t], 0.f);
    __syncthreads();
    // SAB (mab5)
    float q5 = matvec_qs(mab_Wq + 5*16384, S1, red, t);
    float v5 = matvec_qs(mab_Wv + 5*16384, S1, red, t);
    if (t < 128) S2[t] = q5 + mab_bq[5*128 + t] + v5 + mab_bv[5*128 + t];
    __syncthreads();
    float m5 = matvec_qs(mab_Wo + 5*16384, S2, red, t);
    if (t < 128) S1[t] = S2[t] + fmaxf(m5 + mab_bo[5*128 + t], 0.f);
    __syncthreads();
    // SAB (mab6)
    float q6 = matvec_qs(mab_Wq + 6*16384, S1, red, t);
    float v6 = matvec_qs(mab_Wv + 6*16384, S1, red, t);
    if (t < 128) S2[t] = q6 + mab_bq[6*128 + t] + v6 + mab_bv[6*128 + t];
    __syncthreads();
    float m6 = matvec_qs(mab_Wo + 6*16384, S2, red, t);
    if (t < 128) S1[t] = S2[t] + fmaxf(m6 + mab_bo[6*128 + t], 0.f);
    __syncthreads();
    // dec linear
    float y = matvec_qs(dec_W, S1, red, t);
    if (t < 128) out[b*768 + t] = y + dec_b[t];
    // prototypes -> rows 1..5
    {
        int p = t >> 7, c = t & 127;
        out[b*768 + (1 + p)*128 + c] = protos[p*128 + c];
        if (t < 128) out[b*768 + 640 + t] = protos[512 + t];
    }
}

extern "C" void kernel_launch(void* const* d_in, const int* in_sizes, int n_in,
                              void* d_out, int out_size, void* d_ws, size_t ws_size,
                              hipStream_t stream)
{
    (void)in_sizes; (void)n_in; (void)out_size; (void)ws_size;
    const int*   node_ids  = (const int*)d_in[0];
    const int*   edge_idx  = (const int*)d_in[1];
    const float* node_embed= (const float*)d_in[3];
    const float* lin_W     = (const float*)d_in[4];
    const float* lin_b     = (const float*)d_in[5];
    const float* gat_W     = (const float*)d_in[6];
    const float* att_src   = (const float*)d_in[7];
    const float* att_dst   = (const float*)d_in[8];
    const float* gat_bias  = (const float*)d_in[9];
    const float* mab_Wq    = (const float*)d_in[10];
    const float* mab_bq    = (const float*)d_in[11];
    const float* mab_Wk    = (const float*)d_in[12];
    const float* mab_bk    = (const float*)d_in[13];
    const float* mab_Wv    = (const float*)d_in[14];
    const float* mab_bv    = (const float*)d_in[15];
    const float* mab_Wo    = (const float*)d_in[16];
    const float* mab_bo    = (const float*)d_in[17];
    const float* isab_I    = (const float*)d_in[18];
    const float* pma_S     = (const float*)d_in[19];
    const float* dec_W     = (const float*)d_in[20];
    const float* dec_b     = (const float*)d_in[21];
    const float* protos    = (const float*)d_in[22];

    float* ws    = (float*)d_ws;
    float* X     = ws + OFF_X;
    float* acc   = ws + OFF_ACC;
    float* X2    = ws + OFF_X2;
    float* a_s   = ws + OFF_AS;
    float* a_d   = ws + OFF_AD;
    float* Wc    = ws + OFF_WC;
    float* bc    = ws + OFF_BC;
    float* qp    = ws + OFF_QP;
    float* wkh   = ws + OFF_WKH;
    float* ckh   = ws + OFF_CKH;
    float* vas   = ws + OFF_VAS;
    float* vad   = ws + OFF_VAD;
    float* bfin  = ws + OFF_BFIN;
    float* csd   = ws + OFF_CSD;
    float* vpod  = ws + OFF_VPOD;
    int*   mask  = (int*)(ws + OFF_MASK);
    int*   deg   = (int*)(ws + OFF_DEG);
    int*   fill  = (int*)(ws + OFF_FILL);
    int*   cnt   = (int*)(ws + OFF_CNT);
    int*   map   = (int*)(ws + OFF_MAP);
    int*   inv   = (int*)(ws + OFF_INV);
    int*   rowp  = (int*)(ws + OFF_ROWPTR);
    int*   colx  = (int*)(ws + OFF_COL);
    float* out   = (float*)d_out;

    hipMemsetAsync(ws + OFF_MASK, 0, ZERO_BYTES, stream);

    prep_kernel<<<66, 256, 0, stream>>>(lin_W, lin_b, gat_W, mab_Wq, mab_bq, isab_I, pma_S,
                                        Wc, bc, qp);
    prep2_kernel<<<8, 256, 0, stream>>>(mab_Wk, mab_bk, qp, Wc, bc, att_src, att_dst, gat_bias,
                                        wkh, ckh, vas, vad, bfin, csd);
    avec_kernel<<<N_NODES/4, 256, 0, stream>>>(node_embed, vas, vad, csd, a_s, a_d);
    maskset_kernel<<<(NROWS + 255)/256, 256, 0, stream>>>(node_ids, mask);
    assign_kernel<<<(N_NODES + 255)/256, 256, 0, stream>>>(mask, map, inv, cnt);
    pass1_kernel<<<(N_ITEMS + 255)/256, 256, 0, stream>>>(edge_idx, map, deg);
    scan_kernel<<<1, 256, 0, stream>>>(deg, rowp);
    pass2_kernel<<<(N_ITEMS + 255)/256, 256, 0, stream>>>(edge_idx, map, rowp, fill, colx);
    agg_kernel<<<NROWS/4, 256, 0, stream>>>(rowp, colx, inv, cnt, a_s, a_d, node_embed, acc);
    // X2 = acc @ Wc + (bc + gat_bias)  over compact rows
    gemm0_kernel<<<NROWS/16, 256, 0, stream>>>(acc, Wc, bfin, X2);
    gather_kernel<<<NROWS/4, 256, 0, stream>>>(node_ids, map, X2, X);

    for (int i = 0; i < 2; ++i) {
        int o = 2*i + 1;
        attn_even_kernel<<<16, 512, 0, stream>>>(X, qp + i*128, wkh + i*512, ckh + i*4,
                                                 mab_Wv + (2*i)*16384, mab_bv + (2*i)*128,
                                                 mab_Wo + (2*i)*16384, mab_bo + (2*i)*128,
                                                 mab_Wv + o*16384, mab_bv + o*128,
                                                 vpod);
        gemm_odd_kernel<<<NROWS/16, 256, 0, stream>>>(X, mab_Wq + o*16384, mab_bq + o*128,
                                                      vpod, mab_Wo + o*16384, mab_bo + o*128,
                                                      X);
    }
    attn_pma_kernel<<<16, 512, 0, stream>>>(X, qp + 256, wkh + 1024, ckh + 8,
                                            mab_Wq, mab_bq, mab_Wv, mab_bv, mab_Wo, mab_bo,
                                            dec_W, dec_b, protos, out);
}